// Round 3
// baseline (260.730 us; speedup 1.0000x reference)
//
#include <hip/hip_runtime.h>
#include <hip/hip_bf16.h>

typedef float f32x4 __attribute__((ext_vector_type(4)));
typedef short bf16x8 __attribute__((ext_vector_type(8)));

#define MFMA16(a, b, c) __builtin_amdgcn_mfma_f32_16x16x32_bf16(a, b, c, 0, 0, 0)

// Problem constants
constexpr int K1      = 940;    // IN_F
constexpr int KP      = 960;    // K padded to mult of 32
constexpr int NP      = 112;    // N=100 padded to 7 tiles of 16
constexpr int OUT1_LD = 128;    // out1 row stride (K for xg GEMM, padded)

__device__ __forceinline__ float sigf(float x) { return 1.f / (1.f + __expf(-x)); }
__device__ __forceinline__ float tanhfast(float x) { return 2.f / (1.f + __expf(-2.f * x)) - 1.f; }

__device__ __forceinline__ short f2b(float x) {
  __hip_bfloat16 b = __float2bfloat16(x);
  return *reinterpret_cast<short*>(&b);
}

// ---------------------------------------------------------------------------
// Prep: fold swapaxes(-1,-2) into the weights, convert fp32->bf16, zero-pad.
// w2[n][k] = bf16(lin_w[n][f]) where k=c10*94+c2*47+c47, f=c10*94+c47*2+c2
// bw2[g][k] = bf16(b_wih[g][k]) zero-padded K 100->128.
// ---------------------------------------------------------------------------
__global__ void prep_kernel(const float* __restrict__ lin_w,
                            const float* __restrict__ b_wih,
                            __hip_bfloat16* __restrict__ w2,
                            __hip_bfloat16* __restrict__ bw2) {
  int idx = blockIdx.x * 256 + threadIdx.x;
  if (idx < NP * KP) {
    int n = idx / KP, k = idx - n * KP;
    float v = 0.f;
    if (n < 100 && k < K1) {
      int c10 = k / 94, rem = k - c10 * 94;
      int c2 = rem / 47, c47 = rem - c2 * 47;
      int f = c10 * 94 + c47 * 2 + c2;
      v = lin_w[n * K1 + f];
    }
    w2[idx] = __float2bfloat16(v);
  } else {
    int i2 = idx - NP * KP;
    if (i2 < 64 * 128) {
      int g = i2 >> 7, k = i2 & 127;
      bw2[i2] = __float2bfloat16((k < 100) ? b_wih[g * 100 + k] : 0.f);
    }
  }
}

// ---------------------------------------------------------------------------
// Phase 1: out1[m][n] = relu(channels[m][:] @ w2[n][:]^T + lin_b[n]).
// A: fp32 rows (3760 B, 16B aligned) -> two float4 loads + cvt per K-step.
// B: bf16 tile staged in LDS [n][k], row stride 40 (2-way bank alias = free).
// ---------------------------------------------------------------------------
__global__ __launch_bounds__(256, 2)
void linear_relu_mfma(const float* __restrict__ ch,
                      const __hip_bfloat16* __restrict__ w2,
                      const float* __restrict__ lin_b,
                      __hip_bfloat16* __restrict__ out1) {
  __shared__ __align__(16) __hip_bfloat16 Bl[NP * 40];
  const int tid = threadIdx.x;
  const int wave = tid >> 6, lane = tid & 63;
  const int l16 = lane & 15, bq = lane >> 4;  // A: m=l16, k=bq*8+j ; B: n=l16
  const int m0 = blockIdx.x * 64 + wave * 16;
  const long arow = (long)(m0 + l16) * K1;

  f32x4 acc[7] = {};
  for (int s = 0; s < 30; ++s) {  // 29 full K-steps + masked tail (k 928..939)
    const int k0 = s * 32;
    __syncthreads();
    // stage B tile: w2[n][k0..k0+31] -> Bl[n][0..31]
    for (int j = tid; j < 448; j += 256) {
      int n = j >> 2, q = j & 3;
      *reinterpret_cast<uint4*>(&Bl[n * 40 + q * 8]) =
          *reinterpret_cast<const uint4*>(&w2[n * KP + k0 + q * 8]);
    }
    // A fragment: 8 fp32 from global, cvt to bf16
    bf16x8 a;
    if (s < 29) {
      const float4* ap = reinterpret_cast<const float4*>(&ch[arow + k0 + bq * 8]);
      float4 lo = ap[0], hi = ap[1];
      a = bf16x8{f2b(lo.x), f2b(lo.y), f2b(lo.z), f2b(lo.w),
                 f2b(hi.x), f2b(hi.y), f2b(hi.z), f2b(hi.w)};
    } else {
#pragma unroll
      for (int j = 0; j < 8; ++j) {
        int k = k0 + bq * 8 + j;
        a[j] = (k < K1) ? f2b(ch[arow + k]) : short(0);
      }
    }
    __syncthreads();
#pragma unroll
    for (int nt = 0; nt < 7; ++nt) {
      bf16x8 b = *reinterpret_cast<const bf16x8*>(&Bl[(nt * 16 + l16) * 40 + bq * 8]);
      acc[nt] = MFMA16(a, b, acc[nt]);
    }
  }
  // Epilogue: C/D layout col=lane&15 (=n), row=(lane>>4)*4+r (=m within tile)
  const int mb = m0 + bq * 4;
#pragma unroll
  for (int nt = 0; nt < 7; ++nt) {
    const int n = nt * 16 + l16;
    const float bias = (n < 100) ? lin_b[n] : 0.f;
#pragma unroll
    for (int r = 0; r < 4; ++r) {
      float v = fmaxf(acc[nt][r] + bias, 0.f);
      out1[(mb + r) * OUT1_LD + n] = __float2bfloat16((n < 100) ? v : 0.f);
    }
  }
#pragma unroll
  for (int r = 0; r < 4; ++r)  // zero pad cols 112..127 (K-pad for xg GEMM)
    out1[(mb + r) * OUT1_LD + 112 + l16] = __float2bfloat16(0.f);
}

// ---------------------------------------------------------------------------
// Phase 2a: xg[m][g] = out1[m][:] @ bw2[g][:]^T + (b_bih[g]+b_bhh[g]), fp32.
// K=128 (zero padded), 4 N-tiles, weights straight from L2 (16 KB).
// ---------------------------------------------------------------------------
__global__ __launch_bounds__(256)
void xg_mfma(const __hip_bfloat16* __restrict__ out1,
             const __hip_bfloat16* __restrict__ bw2,
             const float* __restrict__ bih,
             const float* __restrict__ bhh,
             float* __restrict__ xg) {
  const int tid = threadIdx.x;
  const int wave = tid >> 6, lane = tid & 63;
  const int l16 = lane & 15, bq = lane >> 4;
  const int m0 = blockIdx.x * 64 + wave * 16;
  const int arow = (m0 + l16) * OUT1_LD;
  f32x4 acc[4] = {};
#pragma unroll
  for (int s = 0; s < 4; ++s) {
    const int k0 = s * 32;
    bf16x8 a = *reinterpret_cast<const bf16x8*>(&out1[arow + k0 + bq * 8]);
#pragma unroll
    for (int nt = 0; nt < 4; ++nt) {
      bf16x8 b = *reinterpret_cast<const bf16x8*>(&bw2[(nt * 16 + l16) * 128 + k0 + bq * 8]);
      acc[nt] = MFMA16(a, b, acc[nt]);
    }
  }
  const int mb = m0 + bq * 4;
#pragma unroll
  for (int nt = 0; nt < 4; ++nt) {
    const int g = nt * 16 + l16;
    const float bias = bih[g] + bhh[g];
#pragma unroll
    for (int r = 0; r < 4; ++r) xg[(mb + r) * 64 + g] = acc[nt][r] + bias;
  }
}

// ---------------------------------------------------------------------------
// Phase 2b: beats LSTM. 4096 seqs, T=8, H=16. Block = 4 seqs x 64 gate-threads.
// Gate order i,f,g,o (PyTorch). fp32 recurrence; fp32 stores to d_out.
// ---------------------------------------------------------------------------
__global__ __launch_bounds__(256)
void beats_lstm(const float* __restrict__ xg,
                const float* __restrict__ whh,
                float* __restrict__ beats) {
  const int tid = threadIdx.x;
  const int sl = tid >> 6, j = tid & 63;
  const int seq = blockIdx.x * 4 + sl;
  __shared__ float hbuf[4][16];
  __shared__ float gact[4][64];
  float wr[16];
#pragma unroll
  for (int u = 0; u < 16; ++u) wr[u] = whh[j * 16 + u];
  float c = 0.f;
  if (j < 16) hbuf[sl][j] = 0.f;
  __syncthreads();
  const float* xs = xg + seq * 8 * 64;
  for (int t = 0; t < 8; ++t) {
    float pre = xs[t * 64 + j];
#pragma unroll
    for (int u = 0; u < 16; ++u) pre += wr[u] * hbuf[sl][u];
    gact[sl][j] = (j >= 32 && j < 48) ? tanhfast(pre) : sigf(pre);
    __syncthreads();
    if (j < 16) {
      c = gact[sl][16 + j] * c + gact[sl][j] * gact[sl][32 + j];
      float hn = gact[sl][48 + j] * tanhfast(c);
      hbuf[sl][j] = hn;
      beats[seq * 128 + t * 16 + j] = hn;
    }
    __syncthreads();
  }
}

// ---------------------------------------------------------------------------
// Phase 3: bars biLSTM. 1024 seqs, T=4(beats), H=32. Block = 1 seq,
// 256 threads = 2 dirs x 128 gates. Reads last-frac beats h from d_out (fp32).
// fwd half -> cols 0..31, bwd half -> cols 32..63 (concat order).
// ---------------------------------------------------------------------------
__global__ __launch_bounds__(256)
void bars_bilstm(const float* __restrict__ fwih, const float* __restrict__ fwhh,
                 const float* __restrict__ fbih, const float* __restrict__ fbhh,
                 const float* __restrict__ rwih, const float* __restrict__ rwhh,
                 const float* __restrict__ rbih, const float* __restrict__ rbhh,
                 const float* __restrict__ beats,
                 float* __restrict__ bars) {
  const int tid = threadIdx.x;
  const int dir = tid >> 7, g = tid & 127;
  const int n = blockIdx.x;
  const float* wih = dir ? rwih : fwih;
  const float* whh = dir ? rwhh : fwhh;
  const float bias = dir ? (rbih[g] + rbhh[g]) : (fbih[g] + fbhh[g]);
  float wi[16], wh[32];
#pragma unroll
  for (int u = 0; u < 16; ++u) wi[u] = wih[g * 16 + u];
#pragma unroll
  for (int u = 0; u < 32; ++u) wh[u] = whh[g * 32 + u];
  __shared__ float xbuf[2][16];
  __shared__ float hbuf[2][32];
  __shared__ float gact[2][128];
  float c = 0.f;
  if (g < 32) hbuf[dir][g] = 0.f;
  __syncthreads();
  for (int t = 0; t < 4; ++t) {
    const int tt = dir ? (3 - t) : t;
    if (g < 16) xbuf[dir][g] = beats[((n * 4 + tt) * 8 + 7) * 16 + g];
    __syncthreads();
    float pre = bias;
#pragma unroll
    for (int u = 0; u < 16; ++u) pre += wi[u] * xbuf[dir][u];
#pragma unroll
    for (int u = 0; u < 32; ++u) pre += wh[u] * hbuf[dir][u];
    gact[dir][g] = (g >= 64 && g < 96) ? tanhfast(pre) : sigf(pre);
    __syncthreads();
    if (g < 32) {
      c = gact[dir][32 + g] * c + gact[dir][g] * gact[dir][64 + g];
      float hn = gact[dir][96 + g] * tanhfast(c);
      hbuf[dir][g] = hn;
      bars[(n * 4 + tt) * 64 + dir * 32 + g] = hn;
    }
    __syncthreads();
  }
}

extern "C" void kernel_launch(void* const* d_in, const int* in_sizes, int n_in,
                              void* d_out, int out_size, void* d_ws, size_t ws_size,
                              hipStream_t stream) {
  const float* ch    = (const float*)d_in[0];
  const float* lin_w = (const float*)d_in[1];
  const float* lin_b = (const float*)d_in[2];
  const float* b_wih = (const float*)d_in[3];
  const float* b_whh = (const float*)d_in[4];
  const float* b_bih = (const float*)d_in[5];
  const float* b_bhh = (const float*)d_in[6];
  const float* f_wih = (const float*)d_in[7];
  const float* f_whh = (const float*)d_in[8];
  const float* f_bih = (const float*)d_in[9];
  const float* f_bhh = (const float*)d_in[10];
  const float* r_wih = (const float*)d_in[11];
  const float* r_whh = (const float*)d_in[12];
  const float* r_bih = (const float*)d_in[13];
  const float* r_bhh = (const float*)d_in[14];

  char* ws = (char*)d_ws;
  __hip_bfloat16* w2   = (__hip_bfloat16*)ws;             // 112*960*2   = 215040 B
  __hip_bfloat16* bw2  = (__hip_bfloat16*)(ws + 215040);  // 64*128*2    = 16384 B
  __hip_bfloat16* out1 = (__hip_bfloat16*)(ws + 231424);  // 32768*128*2 = 8388608 B
  float*          xg   = (float*)(ws + 8620032);          // 32768*64*4  = 8388608 B
  float*          out  = (float*)d_out;

  prep_kernel<<<452, 256, 0, stream>>>(lin_w, b_wih, w2, bw2);
  linear_relu_mfma<<<512, 256, 0, stream>>>(ch, w2, lin_b, out1);
  xg_mfma<<<512, 256, 0, stream>>>(out1, bw2, b_bih, b_bhh, xg);
  beats_lstm<<<1024, 256, 0, stream>>>(xg, b_whh, out);
  bars_bilstm<<<1024, 256, 0, stream>>>(f_wih, f_whh, f_bih, f_bhh,
                                        r_wih, r_whh, r_bih, r_bhh,
                                        out, out + 524288);
}